// Round 3
// baseline (240.296 us; speedup 1.0000x reference)
//
#include <hip/hip_runtime.h>

// GridSpatialIntegral: out[:,0] = cumsum_x(in[:,0]); out[:,1] = cumsum_y(in[:,1])
// [B=64, C=2, 512, 512] fp32. Memory-bound: 134 MB read + 134 MB write, floor ~45-48 us.
//
// Single fused launch, 512-thread blocks (8 waves), __launch_bounds__(512,4)
// pins VGPR<=128 -> 2 blocks/CU guaranteed (x- and y-blocks co-reside, mixing
// their streams per CU):
//   blocks [0, 256):    channel 1 (y-scan) — 128-col x 512-row tile per block
//   blocks [256, 768):  channel 0 (x-scan) — persistent: 64 rows per block,
//                       8 consecutive rows per wave, software-pipelined.
//
// R3 change: x-path request-stream continuity. Was 4096 tiny blocks, each
// draining to 0 outstanding loads at its boundary (addr setup + launch + full
// ~900cyc latency refill, ~16 boundaries per CU slot = 3-8 us dead bus time).
// Now each wave streams 8 consecutive rows with next-row loads issued before
// the current row's scan/store (s_waitcnt vmcnt(2) pattern), boundaries 16->2.
// Lane layout reverted to interleaved (R1 proved 32B-interleave == dense for
// BW); single 6-step shfl scan per row.

#define W 512
#define NB 64
#define YBLOCKS (NB * 4)          // 256
#define XBLOCKS 512               // 512 blocks * 8 waves * 8 rows = 32768 rows
#define GRID (YBLOCKS + XBLOCKS)

typedef float v4f __attribute__((ext_vector_type(4)));   // clang vector: NT-builtin OK

__global__ __launch_bounds__(512, 4)
void gsi_kernel(const float* __restrict__ in, float* __restrict__ out) {
    __shared__ v4f seg[16][32];    // y-path segment sums (8 KB)
    const int tid = threadIdx.x;

    if (blockIdx.x < YBLOCKS) {
        // -------- channel 1: inclusive scan along strided y --------
        // 512 threads = 32 tx (float4 cols, 512B/row-chunk) x 16 ty (16-row segs).
        // Column processed as two 256-row halves; carry propagates in registers.
        // 16-row-deep load batches keep the slot's request pipe full.
        const int bi = blockIdx.x;
        const int b  = bi >> 2;
        const int x0 = (bi & 3) << 7;        // 128-column tile
        const int tx = tid & 31;
        const int ty = tid >> 5;             // 0..15

        const size_t base = (size_t)b * (2 * W * W) + (size_t)(W * W)
                          + (size_t)(ty * 16) * W + (size_t)x0 + (size_t)(tx * 4);
        const v4f* ip = (const v4f*)(in + base);
        v4f*       op = (v4f*)(out + base);
        // row stride in v4f units: W/4 = 128; half stride: 256 rows = 32768 v4f

        v4f d[16];
        v4f carry = (v4f)(0.f);

        #pragma unroll
        for (int h = 0; h < 2; ++h) {
            const int hb = h * 32768;
            v4f sum = (v4f)(0.f);
            #pragma unroll
            for (int k = 0; k < 16; ++k) {
                d[k] = __builtin_nontemporal_load(&ip[hb + k * 128]);
                sum += d[k];
            }

            seg[ty][tx] = sum;
            __syncthreads();

            v4f acc = carry;
            v4f tot = (v4f)(0.f);
            #pragma unroll
            for (int j = 0; j < 16; ++j) {
                v4f s = seg[j][tx];
                tot += s;
                if (j < ty) acc += s;
            }
            carry += tot;
            __syncthreads();     // seg reusable in next half

            #pragma unroll
            for (int k = 0; k < 16; ++k) {
                acc += d[k];
                __builtin_nontemporal_store(acc, &op[hb + k * 128]);
            }
        }
    } else {
        // -------- channel 0: inclusive scan along contiguous x --------
        // Persistent: wave owns 8 consecutive rows (16 KB contiguous stream),
        // pipelined one row ahead so outstanding loads never drain.
        const int wave = tid >> 6;                       // 0..7
        const int lane = tid & 63;
        const int row0 = ((blockIdx.x - YBLOCKS) << 6) + (wave << 3); // 8 rows
        const int b    = row0 >> 9;
        const int y    = row0 & 511;        // 64 | 512: no batch crossing in 8 rows
        const size_t base = (size_t)b * (2 * W * W) + (size_t)y * W;

        const v4f* ip = (const v4f*)(in + base);
        v4f*       op = (v4f*)(out + base);
        const int li = lane * 2;            // interleaved: lane owns 8 consec floats

        v4f a0 = __builtin_nontemporal_load(&ip[li]);
        v4f a1 = __builtin_nontemporal_load(&ip[li + 1]);

        #pragma unroll
        for (int r = 0; r < 8; ++r) {
            v4f b0, b1;
            if (r < 7) {    // prefetch next row before consuming current
                b0 = __builtin_nontemporal_load(&ip[(r + 1) * 128 + li]);
                b1 = __builtin_nontemporal_load(&ip[(r + 1) * 128 + li + 1]);
            }

            float e0 = a0.x;
            float e1 = e0 + a0.y;
            float e2 = e1 + a0.z;
            float e3 = e2 + a0.w;
            float e4 = e3 + a1.x;
            float e5 = e4 + a1.y;
            float e6 = e5 + a1.z;
            float e7 = e6 + a1.w;

            float s = e7;
            #pragma unroll
            for (int off = 1; off < 64; off <<= 1) {
                float t = __shfl_up(s, off, 64);
                if (lane >= off) s += t;
            }
            const float p = s - e7;         // exclusive prefix of lane totals

            v4f o0 = {e0 + p, e1 + p, e2 + p, e3 + p};
            v4f o1 = {e4 + p, e5 + p, e6 + p, e7 + p};
            __builtin_nontemporal_store(o0, &op[r * 128 + li]);
            __builtin_nontemporal_store(o1, &op[r * 128 + li + 1]);

            if (r < 7) { a0 = b0; a1 = b1; }
        }
    }
}

extern "C" void kernel_launch(void* const* d_in, const int* in_sizes, int n_in,
                              void* d_out, int out_size, void* d_ws, size_t ws_size,
                              hipStream_t stream) {
    const float* in  = (const float*)d_in[0];
    float*       out = (float*)d_out;
    (void)in_sizes; (void)n_in; (void)out_size; (void)d_ws; (void)ws_size;
    gsi_kernel<<<dim3(GRID), dim3(512), 0, stream>>>(in, out);
}

// Round 4
// 221.678 us; speedup vs baseline: 1.0840x; 1.0840x over previous
//
#include <hip/hip_runtime.h>

// GridSpatialIntegral: out[:,0] = cumsum_x(in[:,0]); out[:,1] = cumsum_y(in[:,1])
// [B=64, C=2, 512, 512] fp32. Memory-bound: 134 MB read + 134 MB write, floor ~43-48 us.
//
// Single fused launch, 512-thread blocks (8 waves):
//   blocks [0, 256):    channel 1 (y-scan) — 128-col x 512-row column tile per block
//   blocks [256, 4352): channel 0 (x-scan) — 8 rows per block, 1 wave per row
//
// Structure = R2 (best, 221.7): 4096 fine-grained x-blocks load-balance the
// grid around the long y-blocks (R3's coarse persistent x-path regressed +18us
// via tail bubbles). y-tiles 128-col -> 512B-dense wave accesses.
//
// R4 change (single variable): drop the NT hint on ALL STORES, keep NT loads.
// Observation: the fastest writer measured on this part is fillBufferAligned
// at 6.7 TB/s with plain stores; our NT-store kernel writes ~30% slower than
// that pace. Theory: gfx950 'nt' store policy (evict-first/streaming) takes a
// lower-efficiency write path than normal write-back; a uniform write-side tax
// would explain why R1-R3's access-pattern changes all moved <4 us.

#define W 512
#define NB 64
#define YBLOCKS (NB * 4)          // 256
#define XBLOCKS (NB * W / 8)      // 4096

typedef float v4f __attribute__((ext_vector_type(4)));   // clang vector: NT-builtin OK

__global__ __launch_bounds__(512)
void gsi_kernel(const float* __restrict__ in, float* __restrict__ out) {
    __shared__ v4f seg[16][32];    // y-path segment sums (8 KB)
    const int tid = threadIdx.x;

    if (blockIdx.x < YBLOCKS) {
        // -------- channel 1: inclusive scan along strided y --------
        // 512 threads = 32 tx (float4 cols, 512B/row-chunk) x 16 ty (16-row segs).
        // Column processed as two 256-row halves; carry propagates in registers.
        const int bi = blockIdx.x;
        const int b  = bi >> 2;
        const int x0 = (bi & 3) << 7;        // 128-column tile
        const int tx = tid & 31;
        const int ty = tid >> 5;             // 0..15

        const size_t base = (size_t)b * (2 * W * W) + (size_t)(W * W)
                          + (size_t)(ty * 16) * W + (size_t)x0 + (size_t)(tx * 4);
        const v4f* ip = (const v4f*)(in + base);
        v4f*       op = (v4f*)(out + base);
        // row stride in v4f units: W/4 = 128; half stride: 256 rows = 32768 v4f

        v4f d[16];
        v4f carry = (v4f)(0.f);

        #pragma unroll
        for (int h = 0; h < 2; ++h) {
            const int hb = h * 32768;
            v4f sum = (v4f)(0.f);
            #pragma unroll
            for (int k = 0; k < 16; ++k) {
                d[k] = __builtin_nontemporal_load(&ip[hb + k * 128]);
                sum += d[k];
            }

            seg[ty][tx] = sum;
            __syncthreads();

            v4f acc = carry;
            v4f tot = (v4f)(0.f);
            #pragma unroll
            for (int j = 0; j < 16; ++j) {
                v4f s = seg[j][tx];
                tot += s;
                if (j < ty) acc += s;
            }
            carry += tot;
            __syncthreads();     // seg reusable in next half

            #pragma unroll
            for (int k = 0; k < 16; ++k) {
                acc += d[k];
                op[hb + k * 128] = acc;          // plain store (R4: NT dropped)
            }
        }
    } else {
        // -------- channel 0: inclusive scan along contiguous x --------
        // One wave per 512-float row. Two dense 1KB segments per row:
        //   seg0 = floats [0,256)   -> lane's chunk at ip[lane]
        //   seg1 = floats [256,512) -> lane's chunk at ip[64+lane]
        const int wave = tid >> 6;                       // 0..7
        const int lane = tid & 63;
        const int row  = ((blockIdx.x - YBLOCKS) << 3) + wave;   // 0..32767
        const int b    = row >> 9;
        const int y    = row & 511;
        const size_t base = (size_t)b * (2 * W * W) + (size_t)y * W;

        const v4f* ip = (const v4f*)(in + base);
        v4f*       op = (v4f*)(out + base);

        v4f v0 = __builtin_nontemporal_load(&ip[lane]);        // dense 1KB
        v4f v1 = __builtin_nontemporal_load(&ip[64 + lane]);   // dense 1KB

        // per-lane inclusive prefixes within each 4-elem chunk
        float e0 = v0.x;
        float e1 = e0 + v0.y;
        float e2 = e1 + v0.z;
        float e3 = e2 + v0.w;
        float f0 = v1.x;
        float f1 = f0 + v1.y;
        float f2 = f1 + v1.z;
        float f3 = f2 + v1.w;

        // two independent wave scans of the chunk totals (ILP-paired shfls)
        const float t0 = e3, t1 = f3;
        float s0 = t0, s1 = t1;
        #pragma unroll
        for (int off = 1; off < 64; off <<= 1) {
            float u0 = __shfl_up(s0, off, 64);
            float u1 = __shfl_up(s1, off, 64);
            if (lane >= off) { s0 += u0; s1 += u1; }
        }
        const float p0 = s0 - t0;                 // excl. prefix within seg 0
        const float T0 = __shfl(s0, 63, 64);      // seg-0 total (broadcast)
        const float p1 = T0 + (s1 - t1);          // seg-1 offset

        v4f o0 = {e0 + p0, e1 + p0, e2 + p0, e3 + p0};
        v4f o1 = {f0 + p1, f1 + p1, f2 + p1, f3 + p1};
        op[lane]      = o0;                       // plain store (R4: NT dropped)
        op[64 + lane] = o1;                       // plain store (R4: NT dropped)
    }
}

extern "C" void kernel_launch(void* const* d_in, const int* in_sizes, int n_in,
                              void* d_out, int out_size, void* d_ws, size_t ws_size,
                              hipStream_t stream) {
    const float* in  = (const float*)d_in[0];
    float*       out = (float*)d_out;
    (void)in_sizes; (void)n_in; (void)out_size; (void)d_ws; (void)ws_size;
    gsi_kernel<<<dim3(YBLOCKS + XBLOCKS), dim3(512), 0, stream>>>(in, out);
}

// Round 5
// 220.570 us; speedup vs baseline: 1.0894x; 1.0050x over previous
//
#include <hip/hip_runtime.h>

// GridSpatialIntegral: out[:,0] = cumsum_x(in[:,0]); out[:,1] = cumsum_y(in[:,1])
// [B=64, C=2, 512, 512] fp32. Memory-bound: 134 MB read + 134 MB write, floor ~43-48 us.
//
// Single fused launch, 512-thread blocks (8 waves):
//   blocks [0, 128):    channel 1 (y-scan) — 256-col x 512-row column tile per block
//   blocks [128, 4224): channel 0 (x-scan) — 8 rows per block, 1 wave per row
//
// Ledger: x-density (R1, null), continuity/persistent x (R3, -regression),
// NT stores (R4, null). Only live lever: y-path DRAM granularity
// (R2: 256B->512B wave accesses = -3.5us).
//
// R5 change (single variable): y granularity 512B -> 1KB. Tile 256 cols wide,
// 512 threads = 64 tx x 8 ty -> a wave's 64 lanes span 64 v4f = 1KB contiguous
// per load/store instruction (same density as the 6.7 TB/s fill). Column done
// in 4 phases of 128 rows (8 ty x 16 rows each), register carry across phases;
// d[16]/LDS footprint unchanged. Price: YBLOCKS 256->128 (carry chain can't
// split); x-pool stays fine-grained for dynamic balance.

#define W 512
#define NB 64
#define YBLOCKS (NB * 2)          // 128
#define XBLOCKS (NB * W / 8)      // 4096

typedef float v4f __attribute__((ext_vector_type(4)));   // clang vector: NT-builtin OK

__global__ __launch_bounds__(512)
void gsi_kernel(const float* __restrict__ in, float* __restrict__ out) {
    __shared__ v4f seg[8][64];     // y-path segment sums (8 KB)
    const int tid = threadIdx.x;

    if (blockIdx.x < YBLOCKS) {
        // -------- channel 1: inclusive scan along strided y --------
        // 512 threads = 64 tx (float4 cols, 1KB/row per wave) x 8 ty (16-row segs).
        // Column processed as four 128-row phases; carry propagates in registers.
        const int bi = blockIdx.x;
        const int b  = bi >> 1;
        const int x0 = (bi & 1) << 8;        // 256-column tile
        const int tx = tid & 63;
        const int ty = tid >> 6;             // 0..7

        const size_t base = (size_t)b * (2 * W * W) + (size_t)(W * W)
                          + (size_t)(ty * 16) * W + (size_t)x0 + (size_t)(tx * 4);
        const v4f* ip = (const v4f*)(in + base);
        v4f*       op = (v4f*)(out + base);
        // row stride in v4f units: W/4 = 128; phase stride: 128 rows = 16384 v4f

        v4f d[16];
        v4f carry = (v4f)(0.f);

        #pragma unroll
        for (int p = 0; p < 4; ++p) {
            const int pb = p * 16384;
            v4f sum = (v4f)(0.f);
            #pragma unroll
            for (int k = 0; k < 16; ++k) {
                d[k] = __builtin_nontemporal_load(&ip[pb + k * 128]);
                sum += d[k];
            }

            seg[ty][tx] = sum;
            __syncthreads();

            v4f acc = carry;
            v4f tot = (v4f)(0.f);
            #pragma unroll
            for (int j = 0; j < 8; ++j) {
                v4f s = seg[j][tx];
                tot += s;
                if (j < ty) acc += s;
            }
            carry += tot;
            __syncthreads();     // seg reusable in next phase

            #pragma unroll
            for (int k = 0; k < 16; ++k) {
                acc += d[k];
                op[pb + k * 128] = acc;
            }
        }
    } else {
        // -------- channel 0: inclusive scan along contiguous x --------
        // One wave per 512-float row. Two dense 1KB segments per row:
        //   seg0 = floats [0,256)   -> lane's chunk at ip[lane]
        //   seg1 = floats [256,512) -> lane's chunk at ip[64+lane]
        const int wave = tid >> 6;                       // 0..7
        const int lane = tid & 63;
        const int row  = ((blockIdx.x - YBLOCKS) << 3) + wave;   // 0..32767
        const int b    = row >> 9;
        const int y    = row & 511;
        const size_t base = (size_t)b * (2 * W * W) + (size_t)y * W;

        const v4f* ip = (const v4f*)(in + base);
        v4f*       op = (v4f*)(out + base);

        v4f v0 = __builtin_nontemporal_load(&ip[lane]);        // dense 1KB
        v4f v1 = __builtin_nontemporal_load(&ip[64 + lane]);   // dense 1KB

        // per-lane inclusive prefixes within each 4-elem chunk
        float e0 = v0.x;
        float e1 = e0 + v0.y;
        float e2 = e1 + v0.z;
        float e3 = e2 + v0.w;
        float f0 = v1.x;
        float f1 = f0 + v1.y;
        float f2 = f1 + v1.z;
        float f3 = f2 + v1.w;

        // two independent wave scans of the chunk totals (ILP-paired shfls)
        const float t0 = e3, t1 = f3;
        float s0 = t0, s1 = t1;
        #pragma unroll
        for (int off = 1; off < 64; off <<= 1) {
            float u0 = __shfl_up(s0, off, 64);
            float u1 = __shfl_up(s1, off, 64);
            if (lane >= off) { s0 += u0; s1 += u1; }
        }
        const float p0 = s0 - t0;                 // excl. prefix within seg 0
        const float T0 = __shfl(s0, 63, 64);      // seg-0 total (broadcast)
        const float p1 = T0 + (s1 - t1);          // seg-1 offset

        v4f o0 = {e0 + p0, e1 + p0, e2 + p0, e3 + p0};
        v4f o1 = {f0 + p1, f1 + p1, f2 + p1, f3 + p1};
        op[lane]      = o0;
        op[64 + lane] = o1;
    }
}

extern "C" void kernel_launch(void* const* d_in, const int* in_sizes, int n_in,
                              void* d_out, int out_size, void* d_ws, size_t ws_size,
                              hipStream_t stream) {
    const float* in  = (const float*)d_in[0];
    float*       out = (float*)d_out;
    (void)in_sizes; (void)n_in; (void)out_size; (void)d_ws; (void)ws_size;
    gsi_kernel<<<dim3(YBLOCKS + XBLOCKS), dim3(512), 0, stream>>>(in, out);
}